// Round 1
// baseline (5490.191 us; speedup 1.0000x reference)
//
#include <hip/hip_runtime.h>
#include <math.h>

#define BATCH 256
#define DIN 512
#define DFEAT 512
#define HSZ 512
#define VOCAB 32000
#define EMB 64
#define SLEN 16

// C = A @ W^T (+ bias). A: [M][K] row-major. W: [N][K] row-major. C row stride = ldc.
template<int BM, int BN, int BK, int TM, int TN>
__global__ __launch_bounds__(256) void gemm_atb(
    const float* __restrict__ A,
    const float* __restrict__ W,
    const float* __restrict__ bias,   // nullable
    float* __restrict__ C, long long ldc,
    int M, int N, int K)
{
    __shared__ float As[BK][BM + 4];
    __shared__ float Bs[BK][BN + 4];
    constexpr int THREADS = (BM / TM) * (BN / TN);
    const int tid = threadIdx.x;
    const int tx = tid % (BN / TN);
    const int ty = tid / (BN / TN);
    const int row0 = blockIdx.y * BM;
    const int col0 = blockIdx.x * BN;

    float acc[TM][TN] = {};

    for (int k0 = 0; k0 < K; k0 += BK) {
        #pragma unroll
        for (int i = tid; i < BM * BK; i += THREADS) {
            int m = i / BK, k = i % BK;
            As[k][m] = A[(long long)(row0 + m) * K + k0 + k];
        }
        #pragma unroll
        for (int i = tid; i < BN * BK; i += THREADS) {
            int n = i / BK, k = i % BK;
            Bs[k][n] = W[(long long)(col0 + n) * K + k0 + k];
        }
        __syncthreads();
        #pragma unroll
        for (int kk = 0; kk < BK; ++kk) {
            float a[TM], b[TN];
            #pragma unroll
            for (int i = 0; i < TM; ++i) a[i] = As[kk][ty * TM + i];
            #pragma unroll
            for (int j = 0; j < TN; ++j) b[j] = Bs[kk][tx * TN + j];
            #pragma unroll
            for (int i = 0; i < TM; ++i)
                #pragma unroll
                for (int j = 0; j < TN; ++j)
                    acc[i][j] = fmaf(a[i], b[j], acc[i][j]);
        }
        __syncthreads();
    }

    #pragma unroll
    for (int i = 0; i < TM; ++i) {
        long long m = row0 + ty * TM + i;
        float* crow = C + m * ldc;
        #pragma unroll
        for (int j = 0; j < TN; ++j) {
            int n = col0 + tx * TN + j;
            float v = acc[i][j];
            if (bias) v += bias[n];
            crow[n] = v;
        }
    }
}

__global__ void init_e_kernel(float* __restrict__ e, const float* __restrict__ sos) {
    int i = blockIdx.x * 256 + threadIdx.x;   // B*E threads
    e[i] = sos[i & (EMB - 1)];
}

// h_new = GRU gate math from precomputed gi = e@W_ih^T, gh = h@W_hh^T (no biases yet)
__global__ void gru_gates_kernel(const float* __restrict__ gi, const float* __restrict__ gh,
                                 const float* __restrict__ b_ih, const float* __restrict__ b_hh,
                                 const float* __restrict__ h_old, float* __restrict__ h_new) {
    int idx = blockIdx.x * 256 + threadIdx.x;       // b*H + j
    int b = idx >> 9, j = idx & (HSZ - 1);
    const float* gib = gi + (long long)b * 3 * HSZ;
    const float* ghb = gh + (long long)b * 3 * HSZ;
    float gir = gib[j] + b_ih[j];
    float giz = gib[j + HSZ] + b_ih[j + HSZ];
    float gin = gib[j + 2 * HSZ] + b_ih[j + 2 * HSZ];
    float ghr = ghb[j] + b_hh[j];
    float ghz = ghb[j + HSZ] + b_hh[j + HSZ];
    float ghn = ghb[j + 2 * HSZ] + b_hh[j + 2 * HSZ];
    float r = 1.0f / (1.0f + expf(-(gir + ghr)));
    float z = 1.0f / (1.0f + expf(-(giz + ghz)));
    float n = tanhf(gin + r * ghn);
    h_new[idx] = (1.0f - z) * n + z * h_old[idx];
}

// per-row argmax over logits row, write symbol (as float) + gather embedding row
__global__ void argmax_embed_kernel(const float* __restrict__ logits_t, long long row_stride,
                                    const float* __restrict__ emb,
                                    float* __restrict__ seq, float* __restrict__ e_next, int t) {
    int b = blockIdx.x;
    int tid = threadIdx.x;
    const float* row = logits_t + (long long)b * row_stride;
    float best = -INFINITY; int bidx = 0x7fffffff;
    for (int v = tid; v < VOCAB; v += 256) {
        float x = row[v];
        if (x > best) { best = x; bidx = v; }
    }
    __shared__ float sv[256];
    __shared__ int   si[256];
    sv[tid] = best; si[tid] = bidx;
    __syncthreads();
    for (int s = 128; s > 0; s >>= 1) {
        if (tid < s) {
            float ov = sv[tid + s]; int oi = si[tid + s];
            if (ov > sv[tid] || (ov == sv[tid] && oi < si[tid])) { sv[tid] = ov; si[tid] = oi; }
        }
        __syncthreads();
    }
    int sym = si[0];
    if (tid == 0) seq[b * SLEN + t] = (float)sym;
    if (tid < EMB) e_next[b * EMB + tid] = emb[(long long)sym * EMB + tid];
}

extern "C" void kernel_launch(void* const* d_in, const int* in_sizes, int n_in,
                              void* d_out, int out_size, void* d_ws, size_t ws_size,
                              hipStream_t stream) {
    const float* x     = (const float*)d_in[0];
    const float* enc_W = (const float*)d_in[1];
    const float* enc_b = (const float*)d_in[2];
    const float* in_W  = (const float*)d_in[3];
    const float* in_b  = (const float*)d_in[4];
    const float* W_ih  = (const float*)d_in[5];
    const float* W_hh  = (const float*)d_in[6];
    const float* b_ih  = (const float*)d_in[7];
    const float* b_hh  = (const float*)d_in[8];
    const float* out_W = (const float*)d_in[9];
    const float* out_b = (const float*)d_in[10];
    const float* emb   = (const float*)d_in[11];
    const float* sos   = (const float*)d_in[12];

    float* ws   = (float*)d_ws;
    float* feat = ws;                       // B*DFEAT
    float* hA   = feat + BATCH * DFEAT;     // B*H
    float* hB   = hA + BATCH * HSZ;         // B*H
    float* ebuf = hB + BATCH * HSZ;         // B*E
    float* gi   = ebuf + BATCH * EMB;       // B*3H
    float* gh   = gi + BATCH * 3 * HSZ;     // B*3H

    float* seq    = (float*)d_out;              // [B][L]
    float* logits = (float*)d_out + BATCH * SLEN; // [B][L][V]

    // encoder -> input_layer -> h0
    gemm_atb<128, 64, 32, 8, 4><<<dim3(DFEAT / 64, BATCH / 128), 256, 0, stream>>>(
        x, enc_W, enc_b, feat, DFEAT, BATCH, DFEAT, DIN);
    gemm_atb<128, 64, 32, 8, 4><<<dim3(HSZ / 64, BATCH / 128), 256, 0, stream>>>(
        feat, in_W, in_b, hA, HSZ, BATCH, HSZ, DFEAT);
    init_e_kernel<<<(BATCH * EMB) / 256, 256, 0, stream>>>(ebuf, sos);

    float* hc = hA;
    float* hn = hB;
    for (int t = 0; t < SLEN; ++t) {
        // gi = e @ W_ih^T   [B, 3H], K=E
        gemm_atb<128, 64, 32, 8, 4><<<dim3(3 * HSZ / 64, BATCH / 128), 256, 0, stream>>>(
            ebuf, W_ih, nullptr, gi, 3 * HSZ, BATCH, 3 * HSZ, EMB);
        // gh = h @ W_hh^T   [B, 3H], K=H
        gemm_atb<128, 64, 32, 8, 4><<<dim3(3 * HSZ / 64, BATCH / 128), 256, 0, stream>>>(
            hc, W_hh, nullptr, gh, 3 * HSZ, BATCH, 3 * HSZ, HSZ);
        // gates -> h_new
        gru_gates_kernel<<<(BATCH * HSZ) / 256, 256, 0, stream>>>(gi, gh, b_ih, b_hh, hc, hn);
        // logits_t = h_new @ out_W^T + out_b  -> strided into d_out [B][L][V]
        gemm_atb<128, 64, 32, 8, 4><<<dim3(VOCAB / 64, BATCH / 128), 256, 0, stream>>>(
            hn, out_W, out_b, logits + (long long)t * VOCAB, (long long)SLEN * VOCAB,
            BATCH, VOCAB, HSZ);
        // argmax + embedding gather for next step
        argmax_embed_kernel<<<BATCH, 256, 0, stream>>>(
            logits + (long long)t * VOCAB, (long long)SLEN * VOCAB, emb, seq, ebuf, t);
        float* tmp = hc; hc = hn; hn = tmp;
    }
}

// Round 2
// 3366.688 us; speedup vs baseline: 1.6307x; 1.6307x over previous
//
#include <hip/hip_runtime.h>
#include <hip/hip_bf16.h>
#include <math.h>

#define BATCH 256
#define DIN 512
#define DFEAT 512
#define HSZ 512
#define VOCAB 32000
#define EMB 64
#define SLEN 16

typedef __attribute__((ext_vector_type(8))) short bf16x8;
typedef __attribute__((ext_vector_type(4))) float f32x4;

// ---------- fp32 SMEM GEMM: C = A @ W^T (+bias). A:[M][K], W:[N][K], C row stride ldc ----------
template<int BM, int BN, int BK, int TM, int TN>
__global__ __launch_bounds__(256) void gemm_atb(
    const float* __restrict__ A,
    const float* __restrict__ W,
    const float* __restrict__ bias,
    float* __restrict__ C, long long ldc,
    int M, int N, int K)
{
    __shared__ float As[BK][BM + 4];
    __shared__ float Bs[BK][BN + 4];
    constexpr int THREADS = (BM / TM) * (BN / TN);
    const int tid = threadIdx.x;
    const int tx = tid % (BN / TN);
    const int ty = tid / (BN / TN);
    const int row0 = blockIdx.y * BM;
    const int col0 = blockIdx.x * BN;

    float acc[TM][TN] = {};

    for (int k0 = 0; k0 < K; k0 += BK) {
        for (int i = tid; i < BM * BK; i += THREADS) {
            int m = i / BK, k = i % BK;
            As[k][m] = A[(long long)(row0 + m) * K + k0 + k];
        }
        for (int i = tid; i < BN * BK; i += THREADS) {
            int n = i / BK, k = i % BK;
            Bs[k][n] = W[(long long)(col0 + n) * K + k0 + k];
        }
        __syncthreads();
        #pragma unroll
        for (int kk = 0; kk < BK; ++kk) {
            float a[TM], b[TN];
            #pragma unroll
            for (int i = 0; i < TM; ++i) a[i] = As[kk][ty * TM + i];
            #pragma unroll
            for (int j = 0; j < TN; ++j) b[j] = Bs[kk][tx * TN + j];
            #pragma unroll
            for (int i = 0; i < TM; ++i)
                #pragma unroll
                for (int j = 0; j < TN; ++j)
                    acc[i][j] = fmaf(a[i], b[j], acc[i][j]);
        }
        __syncthreads();
    }

    #pragma unroll
    for (int i = 0; i < TM; ++i) {
        long long m = row0 + ty * TM + i;
        float* crow = C + m * ldc;
        #pragma unroll
        for (int j = 0; j < TN; ++j) {
            int n = col0 + tx * TN + j;
            float v = acc[i][j];
            if (bias) v += bias[n];
            crow[n] = v;
        }
    }
}

// ---------- bf16 split helpers ----------
__device__ inline unsigned bf16_rne(float x) {
    union { float f; unsigned u; } u; u.f = x;
    unsigned r = u.u + 0x7fff + ((u.u >> 16) & 1);
    return r >> 16;
}
__device__ inline unsigned split_pack(float x) {
    unsigned hi = bf16_rne(x);
    union { unsigned u; float f; } h; h.u = hi << 16;
    unsigned lo = bf16_rne(x - h.f);
    return (lo << 16) | hi;   // bf16 pair [hi, lo] at elems 2k, 2k+1
}

// out_W [V][H] fp32 -> Wp [V][H] u32 (= [V][2H] bf16 interleaved hi/lo)
__global__ void split_w_kernel(const float* __restrict__ W, unsigned* __restrict__ Wp, int n) {
    int i = blockIdx.x * 256 + threadIdx.x;
    if (i < n) Wp[i] = split_pack(W[i]);
}

__global__ void init_e_kernel(float* __restrict__ e, const float* __restrict__ sos) {
    int i = blockIdx.x * 256 + threadIdx.x;
    e[i] = sos[i & (EMB - 1)];
}

// GRU gates; also writes bf16 hi/lo split of h_new for the MFMA logits GEMM
__global__ void gru_gates_kernel(const float* __restrict__ gi, const float* __restrict__ gh,
                                 const float* __restrict__ b_ih, const float* __restrict__ b_hh,
                                 const float* __restrict__ h_old, float* __restrict__ h_new,
                                 unsigned* __restrict__ hsplit) {
    int idx = blockIdx.x * 256 + threadIdx.x;       // b*H + j
    int b = idx >> 9, j = idx & (HSZ - 1);
    const float* gib = gi + (long long)b * 3 * HSZ;
    const float* ghb = gh + (long long)b * 3 * HSZ;
    float gir = gib[j] + b_ih[j];
    float giz = gib[j + HSZ] + b_ih[j + HSZ];
    float gin = gib[j + 2 * HSZ] + b_ih[j + 2 * HSZ];
    float ghr = ghb[j] + b_hh[j];
    float ghz = ghb[j + HSZ] + b_hh[j + HSZ];
    float ghn = ghb[j + 2 * HSZ] + b_hh[j + 2 * HSZ];
    float r = 1.0f / (1.0f + expf(-(gir + ghr)));
    float z = 1.0f / (1.0f + expf(-(giz + ghz)));
    float n = tanhf(gin + r * ghn);
    float h = (1.0f - z) * n + z * h_old[idx];
    h_new[idx] = h;
    if (hsplit) hsplit[idx] = split_pack(h);
}

// ---------- MFMA logits GEMM: C = Ap @ Wp^T + bias, K'=1024 bf16 ----------
// Ap: [BATCH][512] u32 (=1024 bf16), Wp: [VOCAB][512] u32. 128x128 tile, 4 waves (2x2),
// global_load_lds(16B) with pre-swizzled source; XOR-swizzled ds_read_b128 (rule #21).
__global__ __launch_bounds__(256) void logits_mfma_kernel(
    const unsigned* __restrict__ Ap,
    const unsigned* __restrict__ Wp,
    const float* __restrict__ bias,
    float* __restrict__ C, long long ldc)
{
    __shared__ char smem[2][16384];   // [0]=A tile 128x64 bf16, [1]=B tile
    const int tid = threadIdx.x;
    const int lane = tid & 63;
    const int wave = tid >> 6;
    const int row0 = blockIdx.y * 128;
    const int col0 = blockIdx.x * 128;
    const int wm = wave >> 1, wn = wave & 1;

    f32x4 acc[4][4] = {};

    // staging: iteration i, wave w stages rows r = i*32 + w*8 + lane/8 (LDS linear),
    // source 16B chunk index = (lane&7) ^ (lane>>3)  [inverse of read-side XOR swizzle]
    const int schunk = (lane & 7) ^ (lane >> 3);
    const long long arow = (long long)(row0 + wave * 8 + (lane >> 3));
    const long long brow = (long long)(col0 + wave * 8 + (lane >> 3));

    for (int k0 = 0; k0 < 1024; k0 += 64) {
        #pragma unroll
        for (int i = 0; i < 4; ++i) {
            const char* gA = (const char*)(Ap + (arow + i * 32) * 512 + (k0 >> 1)) + schunk * 16;
            const char* gB = (const char*)(Wp + (brow + i * 32) * 512 + (k0 >> 1)) + schunk * 16;
            char* lA = &smem[0][i * 4096 + wave * 1024];
            char* lB = &smem[1][i * 4096 + wave * 1024];
            __builtin_amdgcn_global_load_lds(
                (const __attribute__((address_space(1))) void*)gA,
                (__attribute__((address_space(3))) void*)lA, 16, 0, 0);
            __builtin_amdgcn_global_load_lds(
                (const __attribute__((address_space(1))) void*)gB,
                (__attribute__((address_space(3))) void*)lB, 16, 0, 0);
        }
        __syncthreads();
        #pragma unroll
        for (int k32 = 0; k32 < 64; k32 += 32) {
            bf16x8 af[4], bfr[4];
            #pragma unroll
            for (int f = 0; f < 4; ++f) {
                int rA = wm * 64 + f * 16 + (lane & 15);
                int byteA = (rA * 128 + (k32 + ((lane >> 4) << 3)) * 2) ^ ((rA & 7) << 4);
                af[f] = *(const bf16x8*)&smem[0][byteA];
                int rB = wn * 64 + f * 16 + (lane & 15);
                int byteB = (rB * 128 + (k32 + ((lane >> 4) << 3)) * 2) ^ ((rB & 7) << 4);
                bfr[f] = *(const bf16x8*)&smem[1][byteB];
            }
            #pragma unroll
            for (int i = 0; i < 4; ++i)
                #pragma unroll
                for (int j = 0; j < 4; ++j)
                    acc[i][j] = __builtin_amdgcn_mfma_f32_16x16x32_bf16(af[i], bfr[j], acc[i][j], 0, 0, 0);
        }
        __syncthreads();
    }

    // C/D layout: col = lane&15, row = (lane>>4)*4 + q   [m89-verified]
    #pragma unroll
    for (int i = 0; i < 4; ++i) {
        #pragma unroll
        for (int q = 0; q < 4; ++q) {
            long long r = row0 + wm * 64 + i * 16 + ((lane >> 4) << 2) + q;
            float* crow = C + r * ldc;
            #pragma unroll
            for (int j = 0; j < 4; ++j) {
                int c = col0 + wn * 64 + j * 16 + (lane & 15);
                crow[c] = acc[i][j][q] + bias[c];
            }
        }
    }
}

// ---------- argmax with exact fp32 refinement of near-max candidates ----------
__global__ void argmax_refine_kernel(const float* __restrict__ logits_t, long long row_stride,
                                     const float* __restrict__ h,
                                     const float* __restrict__ out_W,
                                     const float* __restrict__ out_b,
                                     const float* __restrict__ emb,
                                     float* __restrict__ seq, float* __restrict__ e_next, int t)
{
    int b = blockIdx.x, tid = threadIdx.x;
    const float* row = logits_t + (long long)b * row_stride;
    float best = -INFINITY;
    for (int v = tid; v < VOCAB; v += 256) best = fmaxf(best, row[v]);
    __shared__ float sv[256];
    sv[tid] = best; __syncthreads();
    for (int s = 128; s > 0; s >>= 1) { if (tid < s) sv[tid] = fmaxf(sv[tid], sv[tid + s]); __syncthreads(); }
    float m = sv[0];

    __shared__ int cand[16];
    __shared__ int ncand;
    __shared__ float rv[16];
    if (tid == 0) ncand = 0;
    __syncthreads();
    const float MARGIN = 0.03f;   // approx-logit error << this
    for (int v = tid; v < VOCAB; v += 256) {
        if (row[v] >= m - MARGIN) {
            int slot = atomicAdd(&ncand, 1);
            if (slot < 16) cand[slot] = v;
        }
    }
    __syncthreads();
    int nc = min(ncand, 16);

    int wave = tid >> 6, lane = tid & 63;
    const float* hrow = h + (long long)b * HSZ;
    for (int ci = wave; ci < nc; ci += 4) {
        int v = cand[ci];
        const float* wrow = out_W + (long long)v * HSZ;
        float s = 0.f;
        for (int k = lane; k < HSZ; k += 64) s = fmaf(hrow[k], wrow[k], s);
        for (int off = 32; off > 0; off >>= 1) s += __shfl_down(s, off, 64);
        if (lane == 0) rv[ci] = s + out_b[v];
    }
    __syncthreads();
    if (tid == 0) {
        float bv = -INFINITY; int sym = cand[0];
        for (int ci = 0; ci < nc; ++ci) {
            float x = rv[ci]; int v = cand[ci];
            if (x > bv || (x == bv && v < sym)) { bv = x; sym = v; }
        }
        seq[b * SLEN + t] = (float)sym;
        sv[0] = (float)sym;
    }
    __syncthreads();
    int sym = (int)sv[0];
    if (tid < EMB) e_next[b * EMB + tid] = emb[(long long)sym * EMB + tid];
}

// ---------- fallback fp32 argmax (round-1) ----------
__global__ void argmax_embed_kernel(const float* __restrict__ logits_t, long long row_stride,
                                    const float* __restrict__ emb,
                                    float* __restrict__ seq, float* __restrict__ e_next, int t) {
    int b = blockIdx.x, tid = threadIdx.x;
    const float* row = logits_t + (long long)b * row_stride;
    float best = -INFINITY; int bidx = 0x7fffffff;
    for (int v = tid; v < VOCAB; v += 256) {
        float x = row[v];
        if (x > best) { best = x; bidx = v; }
    }
    __shared__ float sv[256];
    __shared__ int   si[256];
    sv[tid] = best; si[tid] = bidx;
    __syncthreads();
    for (int s = 128; s > 0; s >>= 1) {
        if (tid < s) {
            float ov = sv[tid + s]; int oi = si[tid + s];
            if (ov > sv[tid] || (ov == sv[tid] && oi < si[tid])) { sv[tid] = ov; si[tid] = oi; }
        }
        __syncthreads();
    }
    int sym = si[0];
    if (tid == 0) seq[b * SLEN + t] = (float)sym;
    if (tid < EMB) e_next[b * EMB + tid] = emb[(long long)sym * EMB + tid];
}

extern "C" void kernel_launch(void* const* d_in, const int* in_sizes, int n_in,
                              void* d_out, int out_size, void* d_ws, size_t ws_size,
                              hipStream_t stream) {
    const float* x     = (const float*)d_in[0];
    const float* enc_W = (const float*)d_in[1];
    const float* enc_b = (const float*)d_in[2];
    const float* in_W  = (const float*)d_in[3];
    const float* in_b  = (const float*)d_in[4];
    const float* W_ih  = (const float*)d_in[5];
    const float* W_hh  = (const float*)d_in[6];
    const float* b_ih  = (const float*)d_in[7];
    const float* b_hh  = (const float*)d_in[8];
    const float* out_W = (const float*)d_in[9];
    const float* out_b = (const float*)d_in[10];
    const float* emb   = (const float*)d_in[11];
    const float* sos   = (const float*)d_in[12];

    float* seq    = (float*)d_out;
    float* logits = (float*)d_out + BATCH * SLEN;

    // workspace layout (MFMA path)
    unsigned* Wp = (unsigned*)d_ws;                           // VOCAB*512 u32
    unsigned* Apb = Wp + (size_t)VOCAB * 512;                 // BATCH*512 u32
    float* feat = (float*)(Apb + (size_t)BATCH * 512);
    float* hA   = feat + BATCH * DFEAT;
    float* hB   = hA + BATCH * HSZ;
    float* ebuf = hB + BATCH * HSZ;
    float* gi   = ebuf + BATCH * EMB;
    float* gh   = gi + BATCH * 3 * HSZ;
    size_t need = (size_t)((char*)(gh + BATCH * 3 * HSZ) - (char*)d_ws);
    bool use_mfma = ws_size >= need;

    if (!use_mfma) {
        // fallback: round-1 fp32 layout
        float* ws = (float*)d_ws;
        feat = ws;
        hA   = feat + BATCH * DFEAT;
        hB   = hA + BATCH * HSZ;
        ebuf = hB + BATCH * HSZ;
        gi   = ebuf + BATCH * EMB;
        gh   = gi + BATCH * 3 * HSZ;
    }

    // encoder -> input_layer -> h0
    gemm_atb<64, 64, 32, 4, 4><<<dim3(DFEAT / 64, BATCH / 64), 256, 0, stream>>>(
        x, enc_W, enc_b, feat, DFEAT, BATCH, DFEAT, DIN);
    gemm_atb<64, 64, 32, 4, 4><<<dim3(HSZ / 64, BATCH / 64), 256, 0, stream>>>(
        feat, in_W, in_b, hA, HSZ, BATCH, HSZ, DFEAT);
    init_e_kernel<<<(BATCH * EMB) / 256, 256, 0, stream>>>(ebuf, sos);

    if (use_mfma) {
        int nW = VOCAB * HSZ;
        split_w_kernel<<<(nW + 255) / 256, 256, 0, stream>>>(out_W, Wp, nW);
    }

    float* hc = hA;
    float* hn = hB;
    for (int t = 0; t < SLEN; ++t) {
        gemm_atb<64, 64, 32, 4, 4><<<dim3(3 * HSZ / 64, BATCH / 64), 256, 0, stream>>>(
            ebuf, W_ih, nullptr, gi, 3 * HSZ, BATCH, 3 * HSZ, EMB);
        gemm_atb<64, 64, 32, 4, 4><<<dim3(3 * HSZ / 64, BATCH / 64), 256, 0, stream>>>(
            hc, W_hh, nullptr, gh, 3 * HSZ, BATCH, 3 * HSZ, HSZ);
        gru_gates_kernel<<<(BATCH * HSZ) / 256, 256, 0, stream>>>(
            gi, gh, b_ih, b_hh, hc, hn, use_mfma ? Apb : nullptr);
        if (use_mfma) {
            logits_mfma_kernel<<<dim3(VOCAB / 128, BATCH / 128), 256, 0, stream>>>(
                Apb, Wp, out_b, logits + (long long)t * VOCAB, (long long)SLEN * VOCAB);
            argmax_refine_kernel<<<BATCH, 256, 0, stream>>>(
                logits + (long long)t * VOCAB, (long long)SLEN * VOCAB,
                hn, out_W, out_b, emb, seq, ebuf, t);
        } else {
            gemm_atb<128, 64, 32, 8, 4><<<dim3(VOCAB / 64, BATCH / 128), 256, 0, stream>>>(
                hn, out_W, out_b, logits + (long long)t * VOCAB, (long long)SLEN * VOCAB,
                BATCH, VOCAB, HSZ);
            argmax_embed_kernel<<<BATCH, 256, 0, stream>>>(
                logits + (long long)t * VOCAB, (long long)SLEN * VOCAB, emb, seq, ebuf, t);
        }
        float* tmp = hc; hc = hn; hn = tmp;
    }
}

// Round 3
// 2710.840 us; speedup vs baseline: 2.0253x; 1.2419x over previous
//
#include <hip/hip_runtime.h>
#include <hip/hip_bf16.h>
#include <math.h>

#define BATCH 256
#define DIN 512
#define DFEAT 512
#define HSZ 512
#define VOCAB 32000
#define EMB 64
#define SLEN 16
#define NTILE 250          // VOCAB / 128
#define MARGIN 0.0625f

typedef __attribute__((ext_vector_type(8))) short bf16x8;
typedef __attribute__((ext_vector_type(4))) float f32x4;

// ---------- fp32 SMEM GEMM: C = A @ W^T (+bias). A:[M][K] stride K, W:[N][K], C row stride ldc ----------
template<int BM, int BN, int BK, int TM, int TN>
__global__ __launch_bounds__(256) void gemm_atb(
    const float* __restrict__ A,
    const float* __restrict__ W,
    const float* __restrict__ bias,
    float* __restrict__ C, long long ldc,
    int M, int N, int K)
{
    __shared__ float As[BK][BM + 4];
    __shared__ float Bs[BK][BN + 4];
    constexpr int THREADS = (BM / TM) * (BN / TN);
    const int tid = threadIdx.x;
    const int tx = tid % (BN / TN);
    const int ty = tid / (BN / TN);
    const int row0 = blockIdx.y * BM;
    const int col0 = blockIdx.x * BN;

    float acc[TM][TN] = {};

    for (int k0 = 0; k0 < K; k0 += BK) {
        for (int i = tid; i < BM * BK; i += THREADS) {
            int m = i / BK, k = i % BK;
            As[k][m] = A[(long long)(row0 + m) * K + k0 + k];
        }
        for (int i = tid; i < BN * BK; i += THREADS) {
            int n = i / BK, k = i % BK;
            Bs[k][n] = W[(long long)(col0 + n) * K + k0 + k];
        }
        __syncthreads();
        #pragma unroll
        for (int kk = 0; kk < BK; ++kk) {
            float a[TM], b[TN];
            #pragma unroll
            for (int i = 0; i < TM; ++i) a[i] = As[kk][ty * TM + i];
            #pragma unroll
            for (int j = 0; j < TN; ++j) b[j] = Bs[kk][tx * TN + j];
            #pragma unroll
            for (int i = 0; i < TM; ++i)
                #pragma unroll
                for (int j = 0; j < TN; ++j)
                    acc[i][j] = fmaf(a[i], b[j], acc[i][j]);
        }
        __syncthreads();
    }

    #pragma unroll
    for (int i = 0; i < TM; ++i) {
        long long m = row0 + ty * TM + i;
        float* crow = C + m * ldc;
        #pragma unroll
        for (int j = 0; j < TN; ++j) {
            int n = col0 + tx * TN + j;
            float v = acc[i][j];
            if (bias) v += bias[n];
            crow[n] = v;
        }
    }
}

// ---------- helpers ----------
__device__ inline unsigned bf16_rne(float x) {
    union { float f; unsigned u; } u; u.f = x;
    unsigned r = u.u + 0x7fff + ((u.u >> 16) & 1);
    return r >> 16;
}

// out_W fp32 -> bf16 (vectorized x4)
__global__ void split_w_bf16(const float* __restrict__ W, ushort* __restrict__ Wb, int n4) {
    int i = blockIdx.x * 256 + threadIdx.x;
    if (i < n4) {
        const float4 v = ((const float4*)W)[i];
        ushort4 o;
        o.x = (ushort)bf16_rne(v.x); o.y = (ushort)bf16_rne(v.y);
        o.z = (ushort)bf16_rne(v.z); o.w = (ushort)bf16_rne(v.w);
        ((ushort4*)Wb)[i] = o;
    }
}

// Wcat [2048][576] + bcat [2048]
__global__ void build_wcat(const float* __restrict__ W_ih, const float* __restrict__ W_hh,
                           const float* __restrict__ b_ih, const float* __restrict__ b_hh,
                           float* __restrict__ Wcat, float* __restrict__ bcat) {
    int i = blockIdx.x * 256 + threadIdx.x;
    if (i < 2048) {
        float bv;
        if (i < 1024)      bv = b_ih[i] + b_hh[i];        // r, z summed
        else if (i < 1536) bv = b_ih[i];                  // gi_n rows (1024..1535)
        else               bv = b_hh[i - 512];            // gh_n rows -> b_hh[1024..1535]
        bcat[i] = bv;
    }
    if (i < 2048 * 576) {
        int g = i / 576, k = i % 576;
        float v;
        if (g < 1024)      v = (k < 64) ? W_ih[g * 64 + k] : W_hh[(long long)g * 512 + (k - 64)];
        else if (g < 1536) v = (k < 64) ? W_ih[g * 64 + k] : 0.f;
        else               v = (k < 64) ? 0.f : W_hh[(long long)(g - 512) * 512 + (k - 64)];
        Wcat[(long long)g * 576 + k] = v;
    }
}

// sos -> Acat e-part
__global__ void init_e_kernel(float* __restrict__ Acat, const float* __restrict__ sos) {
    int i = blockIdx.x * 256 + threadIdx.x;   // B*E
    Acat[(long long)(i >> 6) * 576 + (i & 63)] = sos[i & 63];
}

// gates from gcat [B][2048]; h updated in-place in Acat col 64+, bf16(h) to hbf
__global__ void gru_gates_cat(const float* __restrict__ gcat, float* __restrict__ Acat,
                              ushort* __restrict__ hbf) {
    int idx = blockIdx.x * 256 + threadIdx.x;   // b*512 + j
    int b = idx >> 9, j = idx & 511;
    const float* g = gcat + (long long)b * 2048;
    float r = 1.0f / (1.0f + expf(-g[j]));
    float z = 1.0f / (1.0f + expf(-g[512 + j]));
    float n = tanhf(g[1024 + j] + r * g[1536 + j]);
    float* hp = Acat + (long long)b * 576 + 64 + j;
    float h = (1.0f - z) * n + z * (*hp);
    *hp = h;
    hbf[idx] = (ushort)bf16_rne(h);
}

// ---------- MFMA logits GEMM: C = Ab @ Wb^T + bias, K=512 bf16, tile 64x128 ----------
__global__ __launch_bounds__(256) void logits_mfma_kernel(
    const ushort* __restrict__ Ab,    // [256][512] bf16
    const ushort* __restrict__ Wb,    // [VOCAB][512] bf16
    const float* __restrict__ bias,
    float* __restrict__ C, long long ldc,
    float* __restrict__ tmaxv, int* __restrict__ tmaxi)   // [256][256]
{
    __shared__ char smem[24576];      // As 8KB + Bs 16KB
    __shared__ float smv[64][2];
    __shared__ int   smi[64][2];
    char* As = smem;
    char* Bs = smem + 8192;
    const int tid = threadIdx.x;
    const int lane = tid & 63;
    const int wave = tid >> 6;
    const int row0 = blockIdx.y * 64;
    const int col0 = blockIdx.x * 128;
    const int wm = wave >> 1, wn = wave & 1;

    f32x4 acc[2][4] = {};

    const int srow = tid >> 3;        // 0..31
    const int sch = tid & 7;

    for (int k0 = 0; k0 < 512; k0 += 64) {
        #pragma unroll
        for (int ra = 0; ra < 2; ++ra) {
            int row = ra * 32 + srow;
            const char* g = (const char*)(Ab + (long long)(row0 + row) * 512 + k0) + ((sch ^ (row & 7)) * 16);
            __builtin_amdgcn_global_load_lds(
                (const __attribute__((address_space(1))) void*)g,
                (__attribute__((address_space(3))) void*)(As + row * 128 + sch * 16), 16, 0, 0);
        }
        #pragma unroll
        for (int rb = 0; rb < 4; ++rb) {
            int row = rb * 32 + srow;
            const char* g = (const char*)(Wb + (long long)(col0 + row) * 512 + k0) + ((sch ^ (row & 7)) * 16);
            __builtin_amdgcn_global_load_lds(
                (const __attribute__((address_space(1))) void*)g,
                (__attribute__((address_space(3))) void*)(Bs + row * 128 + sch * 16), 16, 0, 0);
        }
        __syncthreads();
        #pragma unroll
        for (int k32 = 0; k32 < 64; k32 += 32) {
            bf16x8 af[2], bfr[4];
            #pragma unroll
            for (int i = 0; i < 2; ++i) {
                int rA = wm * 32 + i * 16 + (lane & 15);
                int byteA = (rA * 128 + (k32 + ((lane >> 4) << 3)) * 2) ^ ((rA & 7) << 4);
                af[i] = *(const bf16x8*)&As[byteA];
            }
            #pragma unroll
            for (int j = 0; j < 4; ++j) {
                int rB = wn * 64 + j * 16 + (lane & 15);
                int byteB = (rB * 128 + (k32 + ((lane >> 4) << 3)) * 2) ^ ((rB & 7) << 4);
                bfr[j] = *(const bf16x8*)&Bs[byteB];
            }
            #pragma unroll
            for (int i = 0; i < 2; ++i)
                #pragma unroll
                for (int j = 0; j < 4; ++j)
                    acc[i][j] = __builtin_amdgcn_mfma_f32_16x16x32_bf16(af[i], bfr[j], acc[i][j], 0, 0, 0);
        }
        __syncthreads();
    }

    // epilogue: bias + store + per-(row, block) max with index
    #pragma unroll
    for (int i = 0; i < 2; ++i) {
        #pragma unroll
        for (int q = 0; q < 4; ++q) {
            int r_local = wm * 32 + i * 16 + ((lane >> 4) << 2) + q;
            long long r = row0 + r_local;
            float* crow = C + r * ldc;
            float mv = -INFINITY; int mc = 0x7fffffff;
            #pragma unroll
            for (int j = 0; j < 4; ++j) {
                int c = col0 + wn * 64 + j * 16 + (lane & 15);
                float v = acc[i][j][q] + bias[c];
                crow[c] = v;
                if (v > mv || (v == mv && c < mc)) { mv = v; mc = c; }
            }
            #pragma unroll
            for (int m = 1; m < 16; m <<= 1) {
                float ov = __shfl_xor(mv, m, 64);
                int oc = __shfl_xor(mc, m, 64);
                if (ov > mv || (ov == mv && oc < mc)) { mv = ov; mc = oc; }
            }
            if ((lane & 15) == 0) { smv[r_local][wn] = mv; smi[r_local][wn] = mc; }
        }
    }
    __syncthreads();
    if (tid < 64) {
        float v0 = smv[tid][0], v1 = smv[tid][1];
        int i0 = smi[tid][0], i1 = smi[tid][1];
        bool t1 = (v1 > v0) || (v1 == v0 && i1 < i0);
        tmaxv[(long long)(row0 + tid) * 256 + blockIdx.x] = t1 ? v1 : v0;
        tmaxi[(long long)(row0 + tid) * 256 + blockIdx.x] = t1 ? i1 : i0;
    }
}

// ---------- argmax via tile-maxes + exact fp32 refinement ----------
__global__ void argmax_refine2(const float* __restrict__ tmaxv, const int* __restrict__ tmaxi,
                               const float* __restrict__ logits_t, long long row_stride,
                               const float* __restrict__ Acat,
                               const float* __restrict__ out_W, const float* __restrict__ out_b,
                               const float* __restrict__ emb,
                               float* __restrict__ seq, float* __restrict__ Acat_e, int t)
{
    int b = blockIdx.x, tid = threadIdx.x;
    float v = (tid < NTILE) ? tmaxv[(long long)b * 256 + tid] : -INFINITY;
    __shared__ float sv[256];
    sv[tid] = v; __syncthreads();
    for (int s = 128; s > 0; s >>= 1) {
        if (tid < s) sv[tid] = fmaxf(sv[tid], sv[tid + s]);
        __syncthreads();
    }
    float M = sv[0];

    __shared__ int qt[32]; __shared__ int nqt;
    if (tid == 0) nqt = 0;
    __syncthreads();
    if (tid < NTILE && v >= M - MARGIN) {
        int s = atomicAdd(&nqt, 1);
        if (s < 32) qt[s] = tid;
    }
    __syncthreads();
    int nq = min(nqt, 32);

    __shared__ int cand[32]; __shared__ int ncand;
    if (tid == 0) ncand = 0;
    __syncthreads();
    const float* row = logits_t + (long long)b * row_stride;
    for (int idx = tid; idx < nq * 128; idx += 256) {
        int c = qt[idx >> 7] * 128 + (idx & 127);
        if (row[c] >= M - MARGIN) {
            int s = atomicAdd(&ncand, 1);
            if (s < 32) cand[s] = c;
        }
    }
    __syncthreads();
    int nc = min(ncand, 32);

    __shared__ float rv[32];
    int wave = tid >> 6, lane = tid & 63;
    const float* hrow = Acat + (long long)b * 576 + 64;
    for (int ci = wave; ci < nc; ci += 4) {
        int vv = cand[ci];
        const float* wrow = out_W + (long long)vv * 512;
        float s = 0.f;
        for (int k = lane; k < 512; k += 64) s = fmaf(hrow[k], wrow[k], s);
        for (int off = 32; off > 0; off >>= 1) s += __shfl_down(s, off, 64);
        if (lane == 0) rv[ci] = s + out_b[vv];
    }
    __syncthreads();
    __shared__ int ssym;
    if (tid == 0) {
        float bv = -INFINITY; int sym = 0x7fffffff;
        for (int ci = 0; ci < nc; ++ci) {
            float x = rv[ci]; int c = cand[ci];
            if (x > bv || (x == bv && c < sym)) { bv = x; sym = c; }
        }
        seq[b * SLEN + t] = (float)sym;
        ssym = sym;
    }
    __syncthreads();
    int sym = ssym;
    if (tid < EMB) Acat_e[(long long)b * 576 + tid] = emb[(long long)sym * EMB + tid];
}

extern "C" void kernel_launch(void* const* d_in, const int* in_sizes, int n_in,
                              void* d_out, int out_size, void* d_ws, size_t ws_size,
                              hipStream_t stream) {
    const float* x     = (const float*)d_in[0];
    const float* enc_W = (const float*)d_in[1];
    const float* enc_b = (const float*)d_in[2];
    const float* in_W  = (const float*)d_in[3];
    const float* in_b  = (const float*)d_in[4];
    const float* W_ih  = (const float*)d_in[5];
    const float* W_hh  = (const float*)d_in[6];
    const float* b_ih  = (const float*)d_in[7];
    const float* b_hh  = (const float*)d_in[8];
    const float* out_W = (const float*)d_in[9];
    const float* out_b = (const float*)d_in[10];
    const float* emb   = (const float*)d_in[11];
    const float* sos   = (const float*)d_in[12];

    float* seq    = (float*)d_out;
    float* logits = (float*)d_out + BATCH * SLEN;

    // workspace layout
    char* p = (char*)d_ws;
    ushort* Wb   = (ushort*)p;            p += (size_t)VOCAB * 512 * 2;   // 32.8 MB
    float* Wcat  = (float*)p;             p += (size_t)2048 * 576 * 4;    // 4.7 MB
    float* bcat  = (float*)p;             p += 2048 * 4;
    float* Acat  = (float*)p;             p += (size_t)BATCH * 576 * 4;   // 0.59 MB
    float* gcat  = (float*)p;             p += (size_t)BATCH * 2048 * 4;  // 2.1 MB
    ushort* hbf  = (ushort*)p;            p += (size_t)BATCH * 512 * 2;   // 0.26 MB
    float* feat  = (float*)p;             p += (size_t)BATCH * DFEAT * 4; // 0.52 MB
    float* tmaxv = (float*)p;             p += (size_t)BATCH * 256 * 4;   // 0.26 MB
    int*   tmaxi = (int*)p;               p += (size_t)BATCH * 256 * 4;

    // prologue (independent pieces)
    split_w_bf16<<<(VOCAB * 512 / 4 + 255) / 256, 256, 0, stream>>>(out_W, Wb, VOCAB * 512 / 4);
    build_wcat<<<(2048 * 576 + 255) / 256, 256, 0, stream>>>(W_ih, W_hh, b_ih, b_hh, Wcat, bcat);
    init_e_kernel<<<(BATCH * EMB) / 256, 256, 0, stream>>>(Acat, sos);
    gemm_atb<64, 64, 32, 4, 4><<<dim3(DFEAT / 64, BATCH / 64), 256, 0, stream>>>(
        x, enc_W, enc_b, feat, DFEAT, BATCH, DFEAT, DIN);
    gemm_atb<64, 64, 32, 4, 4><<<dim3(HSZ / 64, BATCH / 64), 256, 0, stream>>>(
        feat, in_W, in_b, Acat + 64, 576, BATCH, HSZ, DFEAT);

    for (int t = 0; t < SLEN; ++t) {
        // gcat = Acat @ Wcat^T + bcat   [256][2048], K=576
        gemm_atb<64, 64, 32, 4, 4><<<dim3(2048 / 64, BATCH / 64), 256, 0, stream>>>(
            Acat, Wcat, bcat, gcat, 2048, BATCH, 2048, 576);
        // gates -> h (in-place in Acat), hbf
        gru_gates_cat<<<(BATCH * HSZ) / 256, 256, 0, stream>>>(gcat, Acat, hbf);
        // logits + tile-max
        logits_mfma_kernel<<<dim3(NTILE, BATCH / 64), 256, 0, stream>>>(
            hbf, Wb, out_b, logits + (long long)t * VOCAB, (long long)SLEN * VOCAB,
            tmaxv, tmaxi);
        // argmax (exact refine) + embedding gather into Acat e-part
        argmax_refine2<<<BATCH, 256, 0, stream>>>(
            tmaxv, tmaxi, logits + (long long)t * VOCAB, (long long)SLEN * VOCAB,
            Acat, out_W, out_b, emb, seq, Acat, t);
    }
}